// Round 18
// baseline (427.028 us; speedup 1.0000x reference)
//
#include <hip/hip_runtime.h>

typedef unsigned short u16;
typedef unsigned int u32;
typedef __attribute__((ext_vector_type(8))) short s16x8;
typedef __attribute__((ext_vector_type(4))) float f32x4;

// Pcat column offsets (bf16 projection buffer, 4096 rows x 4096 cols)
#define C_QSA 0
#define C_KSA 512
#define C_VSA 1024
#define C_QA  1536
#define C_KA  2048
#define C_QR  2560
#define C_KR  3072
#define C_SV  3584
#define LDP   4096

__device__ __forceinline__ u16 f2bf(float f) {
    union { float f; unsigned u; } v; v.f = f;
    return (u16)((v.u + 0x7FFFu + ((v.u >> 16) & 1u)) >> 16);  // RNE
}
__device__ __forceinline__ float bf2f(u16 h) {
    union { unsigned u; float f; } v; v.u = ((unsigned)h) << 16; return v.f;
}
__device__ __forceinline__ float fexp(float y) {
    return __builtin_exp2f(y * 1.4426950408889634f);
}
__device__ __forceinline__ float ftanh(float x) {
    float e = __builtin_exp2f(x * 2.885390081777927f);    // exp(2x)
    return 1.f - 2.f / (e + 1.f);
}
__device__ __forceinline__ f32x4 mfma16(s16x8 a, s16x8 b, f32x4 c) {
    return __builtin_amdgcn_mfma_f32_16x16x32_bf16(a, b, c, 0, 0, 0);
}
// async global->LDS, 16B per lane; LDS dest = wave-uniform base + lane*16
__device__ __forceinline__ void gload16(const u16* g, u16* l) {
    __builtin_amdgcn_global_load_lds(
        (const __attribute__((address_space(1))) void*)g,
        (__attribute__((address_space(3))) void*)l, 16, 0, 0);
}

// ---------------- converts / transposes ----------------

// both f32->bf16 converts in one launch (4096 blocks; first half x, second sym)
__global__ void cvt2_f32_bf16(const float* __restrict__ a, const float* __restrict__ b,
                              u16* __restrict__ oa, u16* __restrict__ ob) {
    int i = (blockIdx.x * 256 + threadIdx.x) * 8;
    const int half = (i >= 4194304) ? 1 : 0;
    const float* in = half ? b : a;
    u16* out = half ? ob : oa;
    int off = i - half * 4194304;
    float4 x = *(const float4*)(in + off);
    float4 y = *(const float4*)(in + off + 4);
    s16x8 o;
    o[0] = (short)f2bf(x.x); o[1] = (short)f2bf(x.y);
    o[2] = (short)f2bf(x.z); o[3] = (short)f2bf(x.w);
    o[4] = (short)f2bf(y.x); o[5] = (short)f2bf(y.y);
    o[6] = (short)f2bf(y.z); o[7] = (short)f2bf(y.w);
    *(s16x8*)(out + off) = o;
}

struct WP { const float* p[10]; };

__global__ void transpose_w(WP wp, u16* __restrict__ WcatT,
                            u16* __restrict__ woSaT, u16* __restrict__ woRaT) {
    const int z = blockIdx.z;
    const float* W;
    u16* Wt;
    int K;
    if (z < 8) { W = wp.p[z]; Wt = WcatT + (size_t)z * 524288; K = 1024; }
    else       { W = wp.p[z]; Wt = (z == 8) ? woSaT : woRaT;   K = 512;  }
    const int N = 512;
    const int kt = blockIdx.x * 32, nt = blockIdx.y * 32;
    if (kt >= K) return;
    __shared__ float t[32][33];
    const int c = threadIdx.x & 31, r0 = threadIdx.x >> 5;
#pragma unroll
    for (int it = 0; it < 4; ++it) {
        int r = it * 8 + r0;
        t[r][c] = W[(size_t)(kt + r) * N + nt + c];
    }
    __syncthreads();
#pragma unroll
    for (int it = 0; it < 4; ++it) {
        int r = it * 8 + r0;
        Wt[(size_t)(nt + r) * K + kt + c] = f2bf(t[c][r]);
    }
}

// Vt/SVt in one launch: z=0..3 -> vT (C_VSA), z=4..7 -> svT (C_SV).
// s' kappa-permuted within each 32-group: new = (j&15)/4*8 + (j>>4)*4 + (j&3)
__global__ void transpose_v2(const u16* __restrict__ P, u16* __restrict__ vT,
                             u16* __restrict__ svT) {
    const int st = blockIdx.x * 32, ht = blockIdx.y * 32;
    const int z = blockIdx.z;
    const int b = z & 3;
    const int colOff = (z < 4) ? C_VSA : C_SV;
    u16* Vt = (z < 4) ? vT : svT;
    __shared__ u16 t[32][34];
    const int c = threadIdx.x & 31, r0 = threadIdx.x >> 5;
#pragma unroll
    for (int it = 0; it < 4; ++it) {
        int r = it * 8 + r0;
        t[r][c] = P[(size_t)(b * 1024 + st + r) * LDP + colOff + ht + c];
    }
    __syncthreads();
    const int cp = ((c & 15) >> 2) * 8 + (c >> 4) * 4 + (c & 3);
#pragma unroll
    for (int it = 0; it < 4; ++it) {
        int r = it * 8 + r0;
        Vt[(size_t)b * 524288 + (size_t)(ht + r) * 1024 + st + cp] = t[c][r];
    }
}

// ---------------- RoPE (standalone, in-place on QSA,KSA,QA,KA regions) --------

__global__ void rope_kernel(u16* __restrict__ P, const float* __restrict__ fcos,
                            const float* __restrict__ fsin) {
    int idx = blockIdx.x * 256 + threadIdx.x;
    int row = idx >> 10;
    int rem = idx & 1023;
    int region = rem >> 8;
    int pr = rem & 255;
    int head = pr >> 5, p = pr & 31;
    int off = (region + (region >> 1)) * 512;
    int col = off + head * 64 + 2 * p;
    int s = row & 1023;
    float c = fcos[s * 32 + p], sn = fsin[s * 32 + p];
    u32* ptr = (u32*)(P + (size_t)row * LDP + col);
    u32 v = *ptr;
    float xr = bf2f((u16)(v & 0xffff)), xi = bf2f((u16)(v >> 16));
    u16 o0 = f2bf(xr * c - xi * sn);
    u16 o1 = f2bf(xr * sn + xi * c);
    *ptr = (u32)o0 | ((u32)o1 << 16);
}

// ---------------- GEMM: BK=64, T2 both-sides XOR swizzle, 2-D XCD chunks ------

template<bool OUT_BF16, bool SWZ>
__global__ __launch_bounds__(256) void gemm_bf16(
    const u16* __restrict__ A, const u16* __restrict__ A2, int lda, int nswitch,
    const u16* __restrict__ Bt, int ldb,
    void* __restrict__ Cp, int ldc, int ccolOff, int K)
{
    __shared__ u16 As[128][64];
    __shared__ u16 Bs[128][64];
    const int tid = threadIdx.x;
    int bx = blockIdx.x, by = blockIdx.y;
    if (SWZ) {
        int lin = by * gridDim.x + bx;
        int k = lin & 7, j = lin >> 3;
        bx = (k & 3) * 8 + (j & 7);
        by = (k >> 2) * 16 + (j >> 3);
    }
    const int m0 = bx * 128, n0 = by * 128;
    const u16* Ause = (A2 != nullptr && n0 >= nswitch) ? A2 : A;
    const int w = tid >> 6, lane = tid & 63;
    const int w32 = w * 32;
    const int wm = (w >> 1) * 64, wn = (w & 1) * 64;
    const int lr = lane & 15, lg = lane >> 4;
    const int srow = lane >> 3;
    const int sc16 = ((lane & 7) ^ srow) * 8;
    f32x4 acc[4][4] = {};

    for (int k0 = 0; k0 < K; k0 += 64) {
        const u16* ga = &Ause[(size_t)(m0 + w32 + srow) * lda + k0 + sc16];
        const u16* gb = &Bt [(size_t)(n0 + w32 + srow) * ldb + k0 + sc16];
        gload16(ga,            &As[w32][0]);
        gload16(ga +  8 * lda, &As[w32 +  8][0]);
        gload16(ga + 16 * lda, &As[w32 + 16][0]);
        gload16(ga + 24 * lda, &As[w32 + 24][0]);
        gload16(gb,            &Bs[w32][0]);
        gload16(gb +  8 * ldb, &Bs[w32 +  8][0]);
        gload16(gb + 16 * ldb, &Bs[w32 + 16][0]);
        gload16(gb + 24 * ldb, &Bs[w32 + 24][0]);
        __syncthreads();
#pragma unroll
        for (int kk = 0; kk < 2; ++kk) {
            s16x8 af[4], bfr[4];
#pragma unroll
            for (int t = 0; t < 4; ++t) {
                const int ca = (((kk * 4 + lg) ^ (lr & 7)) * 8);
                af[t]  = *(const s16x8*)&As[wm + t * 16 + lr][ca];
                bfr[t] = *(const s16x8*)&Bs[wn + t * 16 + lr][ca];
            }
#pragma unroll
            for (int i = 0; i < 4; ++i)
#pragma unroll
                for (int j = 0; j < 4; ++j)
                    acc[i][j] = mfma16(af[i], bfr[j], acc[i][j]);
        }
        __syncthreads();
    }
#pragma unroll
    for (int i = 0; i < 4; ++i)
#pragma unroll
        for (int j = 0; j < 4; ++j)
#pragma unroll
            for (int r = 0; r < 4; ++r) {
                int row = m0 + wm + i * 16 + lg * 4 + r;
                int col = n0 + wn + j * 16 + lr;
                float val = acc[i][j][r];
                if (OUT_BF16)
                    ((u16*)Cp)[(size_t)row * ldc + ccolOff + col] = f2bf(val);
                else
                    ((float*)Cp)[(size_t)row * ldc + ccolOff + col] = val;
            }
}

// ---------------- FUSED attention: RA + SA at WAVE level ----------------------
// 512 blocks x 512 thr, R13 slot mapping: bid&7 = (s,b) XCD slot, xt=63-(bid>>3).
// Wave w handles head w for BOTH streams on the SAME (b, xt, parity s) tiles:
//   RA: QK^T + rel channel w (relT dbuf, 1 barrier/64j) -> bf16 o + f32 l,rm
//   SA: QK^T + PV (barrier-free, inserted after the barrier region -> fills
//       RA's stalls with independent MFMA/exp work; same XCD affinity)
// Unstabilized softmax both streams. merge_both combines parity splits.

__global__ __launch_bounds__(512, 4) void attn_both(
    u16* __restrict__ P, const u16* __restrict__ Vt, const u16* __restrict__ SVt,
    u16* __restrict__ opRA, float* __restrict__ mlrRA,
    u16* __restrict__ opSA, float* __restrict__ lSA)
{
    const int bid = blockIdx.x;
    const int slot = bid & 7;
    const int b = slot & 3, s = slot >> 2;
    const int xt = 63 - (bid >> 3);
    const int w = threadIdx.x >> 6, lane = threadIdx.x & 63;
    const int lr = lane & 15, lg = lane >> 4;
    const int h = w;
    const size_t rowBase = (size_t)b * 1024;
    const int i0 = xt * 16;
    const int ir = i0 + lr;

    __shared__ float relT[2][2][32][16][8];   // [dbuf][tileAB][j-local][i][swz slot]

    const u16* Kbase  = P + rowBase * LDP + (C_KA + h * 64);
    const u16* KRbase = P + rowBase * LDP + (C_KR + h * 64);
    const u16* KSbase = P + rowBase * LDP + (C_KSA + h * 64);
    const u16* Vb  = SVt + ((size_t)(b * 8 + h)) * 65536;
    const u16* Vsb = Vt  + ((size_t)(b * 8 + h)) * 65536;

    s16x8 qf[2], qrf[2], qs[2];
    {
        const u16* q = P + (rowBase + ir) * LDP + (C_QA + h * 64) + lg * 8;
        qf[0] = *(const s16x8*)q; qf[1] = *(const s16x8*)(q + 32);
        const u16* qr = P + (rowBase + ir) * LDP + (C_QR + h * 64) + lg * 8;
        qrf[0] = *(const s16x8*)qr; qrf[1] = *(const s16x8*)(qr + 32);
        const u16* qq = P + (rowBase + ir) * LDP + (C_QSA + h * 64) + lg * 8;
        qs[0] = *(const s16x8*)qq; qs[1] = *(const s16x8*)(qq + 32);
    }
    f32x4 o[4] = {}, os[4] = {};
    float rmr[8] = {};                      // rotated slots: slot k = channel (k-lr)&7
    float l = 0.f, ls = 0.f;
    const int njt = (xt >> 1) + 1;
    const int cnt = (njt - s + 1) >> 1;     // tiles of parity s
    const int npair = (cnt + 1) >> 1;
    const int slotw = (w + lr) & 7;

    for (int u = 0; u < npair; ++u) {
        const int j0a = (s + 4 * u) * 32;
        const bool actB = (2 * u + 1) < cnt;        // block-uniform
        const int j0b = actB ? j0a + 64 : j0a;      // clamp for safe loads
        // ================= RA section (R13 v5) =================
        {
            s16x8 kfA[2][2], krA[2][2], kfB[2][2], krB[2][2], vfA[4], vfB[4];
#pragma unroll
            for (int sub = 0; sub < 2; ++sub) {
                const u16* kp = Kbase + (size_t)(j0a + sub * 16 + lr) * LDP + lg * 8;
                kfA[sub][0] = *(const s16x8*)kp;  kfA[sub][1] = *(const s16x8*)(kp + 32);
                const u16* krp = KRbase + (size_t)(j0a + sub * 16 + lr) * LDP + lg * 8;
                krA[sub][0] = *(const s16x8*)krp; krA[sub][1] = *(const s16x8*)(krp + 32);
                kp = Kbase + (size_t)(j0b + sub * 16 + lr) * LDP + lg * 8;
                kfB[sub][0] = *(const s16x8*)kp;  kfB[sub][1] = *(const s16x8*)(kp + 32);
                krp = KRbase + (size_t)(j0b + sub * 16 + lr) * LDP + lg * 8;
                krB[sub][0] = *(const s16x8*)krp; krB[sub][1] = *(const s16x8*)(krp + 32);
            }
#pragma unroll
            for (int ds = 0; ds < 4; ++ds) {
                vfA[ds] = *(const s16x8*)(Vb + (size_t)(ds * 16 + lr) * 1024 + j0a + 8 * lg);
                vfB[ds] = *(const s16x8*)(Vb + (size_t)(ds * 16 + lr) * 1024 + j0b + 8 * lg);
            }
            f32x4 scA[2] = {{0.f,0.f,0.f,0.f},{0.f,0.f,0.f,0.f}};
            f32x4 scB[2] = {{0.f,0.f,0.f,0.f},{0.f,0.f,0.f,0.f}};
            f32x4 rtA[2] = {{0.f,0.f,0.f,0.f},{0.f,0.f,0.f,0.f}};
            f32x4 rtB[2] = {{0.f,0.f,0.f,0.f},{0.f,0.f,0.f,0.f}};
#pragma unroll
            for (int sub = 0; sub < 2; ++sub) {
                scA[sub] = mfma16(kfA[sub][0], qf[0], scA[sub]);
                scA[sub] = mfma16(kfA[sub][1], qf[1], scA[sub]);
                rtA[sub] = mfma16(krA[sub][0], qrf[0], rtA[sub]);
                rtA[sub] = mfma16(krA[sub][1], qrf[1], rtA[sub]);
                scB[sub] = mfma16(kfB[sub][0], qf[0], scB[sub]);
                scB[sub] = mfma16(kfB[sub][1], qf[1], scB[sub]);
                rtB[sub] = mfma16(krB[sub][0], qrf[0], rtB[sub]);
                rtB[sub] = mfma16(krB[sub][1], qrf[1], rtB[sub]);
            }
            float pA[2][4], pB[2][4];
#pragma unroll
            for (int sub = 0; sub < 2; ++sub)
#pragma unroll
                for (int r = 0; r < 4; ++r) {
                    int jA = j0a + sub * 16 + 4 * lg + r;
                    int jB = j0b + sub * 16 + 4 * lg + r;
                    pA[sub][r] = (jA <= ir) ? fexp(scA[sub][r] * 0.125f) : 0.f;
                    pB[sub][r] = (actB && jB <= ir) ? fexp(scB[sub][r] * 0.125f) : 0.f;
                    l += pA[sub][r] + pB[sub][r];
                }
#pragma unroll
            for (int sub = 0; sub < 2; ++sub)
#pragma unroll
                for (int r = 0; r < 4; ++r) {
                    int jp = sub * 16 + 4 * lg + r;
                    relT[u & 1][0][jp][lr][slotw] = ftanh(rtA[sub][r] * 0.125f);
                    relT[u & 1][1][jp][lr][slotw] = ftanh(rtB[sub][r] * 0.125f);
                }
            __syncthreads();
#pragma unroll
            for (int sub = 0; sub < 2; ++sub)
#pragma unroll
                for (int r = 0; r < 4; ++r) {
                    int jp = sub * 16 + 4 * lg + r;
                    f32x4 a  = *(const f32x4*)&relT[u & 1][0][jp][lr][0];
                    f32x4 bb = *(const f32x4*)&relT[u & 1][0][jp][lr][4];
                    float pv = pA[sub][r];
#pragma unroll
                    for (int k = 0; k < 4; ++k) {
                        rmr[k]     += pv * a[k];
                        rmr[4 + k] += pv * bb[k];
                    }
                    a  = *(const f32x4*)&relT[u & 1][1][jp][lr][0];
                    bb = *(const f32x4*)&relT[u & 1][1][jp][lr][4];
                    pv = pB[sub][r];
#pragma unroll
                    for (int k = 0; k < 4; ++k) {
                        rmr[k]     += pv * a[k];
                        rmr[4 + k] += pv * bb[k];
                    }
                }
            s16x8 paA, paB;
#pragma unroll
            for (int r = 0; r < 4; ++r) {
                paA[r]     = (short)f2bf(pA[0][r]);
                paA[4 + r] = (short)f2bf(pA[1][r]);
                paB[r]     = (short)f2bf(pB[0][r]);
                paB[4 + r] = (short)f2bf(pB[1][r]);
            }
#pragma unroll
            for (int ds = 0; ds < 4; ++ds) {
                o[ds] = mfma16(paA, vfA[ds], o[ds]);
                o[ds] = mfma16(paB, vfB[ds], o[ds]);
            }
        }
        // ================= SA section (barrier-free) =================
#pragma unroll
        for (int tb = 0; tb < 2; ++tb) {
            if (tb == 1 && !actB) break;
            const int j0 = tb ? j0b : j0a;
            s16x8 ks[2][2], vs[4];
#pragma unroll
            for (int sub = 0; sub < 2; ++sub) {
                const u16* kp = KSbase + (size_t)(j0 + sub * 16 + lr) * LDP + lg * 8;
                ks[sub][0] = *(const s16x8*)kp;
                ks[sub][1] = *(const s16x8*)(kp + 32);
            }
#pragma unroll
            for (int ds = 0; ds < 4; ++ds)
                vs[ds] = *(const s16x8*)(Vsb + (size_t)(ds * 16 + lr) * 1024 + j0 + 8 * lg);
            f32x4 sc[2] = {{0.f,0.f,0.f,0.f},{0.f,0.f,0.f,0.f}};
#pragma unroll
            for (int sub = 0; sub < 2; ++sub) {
                sc[sub] = mfma16(ks[sub][0], qs[0], sc[sub]);
                sc[sub] = mfma16(ks[sub][1], qs[1], sc[sub]);
            }
            s16x8 pa;
#pragma unroll
            for (int sub = 0; sub < 2; ++sub)
#pragma unroll
                for (int r = 0; r < 4; ++r) {
                    int j = j0 + sub * 16 + 4 * lg + r;
                    float p = (j <= ir) ? fexp(sc[sub][r] * 0.125f) : 0.f;
                    ls += p;
                    pa[sub * 4 + r] = (short)f2bf(p);
                }
#pragma unroll
            for (int ds = 0; ds < 4; ++ds) os[ds] = mfma16(pa, vs[ds], os[ds]);
        }
    }

    // ---- epilogue ----
    l  += __shfl_xor(l, 16);  l  += __shfl_xor(l, 32);
    ls += __shfl_xor(ls, 16); ls += __shfl_xor(ls, 32);
#pragma unroll
    for (int k = 0; k < 8; ++k) {
        float v = rmr[k];
        v += __shfl_xor(v, 16);
        v += __shfl_xor(v, 32);
        rmr[k] = v;
    }
    float g[8], t0[8];
    const int t = lr & 7;
#pragma unroll
    for (int k = 0; k < 8; ++k) g[k] = rmr[k];
#pragma unroll
    for (int k = 0; k < 8; ++k) t0[k] = (t & 1) ? g[(k + 1) & 7] : g[k];
#pragma unroll
    for (int k = 0; k < 8; ++k) g[k]  = (t & 2) ? t0[(k + 2) & 7] : t0[k];
#pragma unroll
    for (int k = 0; k < 8; ++k) t0[k] = (t & 4) ? g[(k + 4) & 7] : g[k];

    const int headRow = (b * 8 + h) * 1024;
#pragma unroll
    for (int ds = 0; ds < 4; ++ds)
#pragma unroll
        for (int r = 0; r < 4; ++r) {
            int row = headRow + i0 + 4 * lg + r;
            opRA[((size_t)row * 2 + s) * 64 + ds * 16 + lr] = f2bf(o[ds][r]);
            opSA[((size_t)row * 2 + s) * 64 + ds * 16 + lr] = f2bf(os[ds][r]);
        }
    if (lg == 0) {
        float* pm = &mlrRA[((size_t)(headRow + i0 + lr) * 2 + s) * 9];
        pm[0] = l;
#pragma unroll
        for (int c = 0; c < 8; ++c) pm[1 + c] = t0[c];
        lSA[(size_t)(headRow + i0 + lr) * 2 + s] = ls;
    }
}

// ---------------- merge: RA (sum splits + wr proj) and SA (sum/normalize) -----

__global__ __launch_bounds__(256) void merge_both(
    const u16* __restrict__ opRA, const float* __restrict__ mlrRA,
    const u16* __restrict__ opSA, const float* __restrict__ lSA,
    const float* __restrict__ wr, u16* __restrict__ P)
{
    const int gid = blockIdx.x * 4 + (threadIdx.x >> 6);   // [0, 32768)
    const int d = threadIdx.x & 63;
    const int i = gid & 1023;
    const int h = (gid >> 10) & 7;
    const int b = gid >> 13;
    // RA
    const float* ml0 = &mlrRA[(size_t)gid * 18];
    const float* ml1 = ml0 + 9;
    float ilt = 1.f / (ml0[0] + ml1[0]);
    float acc = (bf2f(opRA[(size_t)gid * 128 + d]) +
                 bf2f(opRA[(size_t)gid * 128 + 64 + d])) * ilt;
#pragma unroll
    for (int c = 0; c < 8; ++c) {
        float rm = (ml0[1 + c] + ml1[1 + c]) * ilt;
        acc += rm * wr[h * 512 + d * 8 + c];
    }
    P[((size_t)(b * 1024 + i)) * LDP + C_QA + h * 64 + d] = f2bf(acc);
    // SA
    float ilts = 1.f / (lSA[(size_t)gid * 2] + lSA[(size_t)gid * 2 + 1]);
    float accs = (bf2f(opSA[(size_t)gid * 128 + d]) +
                  bf2f(opSA[(size_t)gid * 128 + 64 + d])) * ilts;
    P[((size_t)(b * 1024 + i)) * LDP + C_QSA + h * 64 + d] = f2bf(accs);
}

// ---------------- launcher ----------------

extern "C" void kernel_launch(void* const* d_in, const int* in_sizes, int n_in,
                              void* d_out, int out_size, void* d_ws, size_t ws_size,
                              hipStream_t stream)
{
    const float* x     = (const float*)d_in[0];
    const float* sym   = (const float*)d_in[1];
    const float* fcos  = (const float*)d_in[2];
    const float* fsin  = (const float*)d_in[3];
    const float* w_qsa = (const float*)d_in[4];
    const float* w_ksa = (const float*)d_in[5];
    const float* w_vsa = (const float*)d_in[6];
    const float* w_osa = (const float*)d_in[7];
    const float* w_qa  = (const float*)d_in[8];
    const float* w_ka  = (const float*)d_in[9];
    const float* w_qr  = (const float*)d_in[10];
    const float* w_kr  = (const float*)d_in[11];
    const float* wr    = (const float*)d_in[12];
    const float* w_sv  = (const float*)d_in[13];
    const float* w_ora = (const float*)d_in[14];

    char* ws = (char*)d_ws;
    u16* xb    = (u16*)(ws);                                  // 8 MB   (dead after proj GEMM)
    u16* symb  = (u16*)(ws + (8u  << 20));                    // 8 MB   (dead after proj GEMM)
    u16* WcatT = (u16*)(ws + (16u << 20));                    // 8 MB   (dead after proj GEMM)
    u16* woSaT = (u16*)(ws + (24u << 20));                    // 512 KB
    u16* woRaT = (u16*)(ws + (24u << 20) + (512u << 10));     // 512 KB
    u16* Pcat  = (u16*)(ws + (25u << 20));                    // 32 MB
    u16* vT    = (u16*)(ws + (57u << 20));                    // 4 MB
    u16* svT   = (u16*)(ws + (61u << 20));                    // 4 MB
    // partials reuse the dead 0..24 MB region after the projection GEMM:
    u16*   opRA  = (u16*)(ws);                                // 8.39 MB (bf16)
    u16*   opSA  = (u16*)(ws + (9u  << 20));                  // 8.39 MB (bf16)
    float* mlrRA = (float*)(ws + (18u << 20));                // 2.36 MB
    float* lSAp  = (float*)(ws + (21u << 20));                // 0.26 MB

    cvt2_f32_bf16<<<4096, 256, 0, stream>>>(x, sym, xb, symb);

    WP wp{{w_qsa, w_ksa, w_vsa, w_qa, w_ka, w_qr, w_kr, w_sv, w_osa, w_ora}};
    transpose_w<<<dim3(32, 16, 10), 256, 0, stream>>>(wp, WcatT, woSaT, woRaT);

    gemm_bf16<true, true><<<dim3(32, 32), 256, 0, stream>>>(
        xb, symb, 1024, C_SV, WcatT, 1024, Pcat, LDP, 0, 1024);

    rope_kernel<<<16384, 256, 0, stream>>>(Pcat, fcos, fsin);

    transpose_v2<<<dim3(32, 16, 8), 256, 0, stream>>>(Pcat, vT, svT);

    attn_both<<<512, 512, 0, stream>>>(Pcat, vT, svT, opRA, mlrRA, opSA, lSAp);
    merge_both<<<8192, 256, 0, stream>>>(opRA, mlrRA, opSA, lSAp, wr, Pcat);

    // merged output projection: cols [0,512) = wo_sa @ sa_out, [512,1024) = wo_ra @ ra_out
    gemm_bf16<false, false><<<dim3(32, 8), 256, 0, stream>>>(
        Pcat + C_QSA, Pcat + C_QA, LDP, 512, woSaT, 512, d_out, 1024, 0, 512);
}

// Round 19
// 202.726 us; speedup vs baseline: 2.1064x; 2.1064x over previous
//
#include <hip/hip_runtime.h>

typedef unsigned short u16;
typedef unsigned int u32;
typedef __attribute__((ext_vector_type(8))) short s16x8;
typedef __attribute__((ext_vector_type(4))) float f32x4;

// Pcat column offsets (bf16 projection buffer, 4096 rows x 4096 cols)
#define C_QSA 0
#define C_KSA 512
#define C_VSA 1024
#define C_QA  1536
#define C_KA  2048
#define C_QR  2560
#define C_KR  3072
#define C_SV  3584
#define LDP   4096

__device__ __forceinline__ u16 f2bf(float f) {
    union { float f; unsigned u; } v; v.f = f;
    return (u16)((v.u + 0x7FFFu + ((v.u >> 16) & 1u)) >> 16);  // RNE
}
__device__ __forceinline__ float bf2f(u16 h) {
    union { unsigned u; float f; } v; v.u = ((unsigned)h) << 16; return v.f;
}
__device__ __forceinline__ float fexp(float y) {
    return __builtin_exp2f(y * 1.4426950408889634f);
}
__device__ __forceinline__ float ftanh(float x) {
    float e = __builtin_exp2f(x * 2.885390081777927f);    // exp(2x)
    return 1.f - 2.f / (e + 1.f);
}
__device__ __forceinline__ f32x4 mfma16(s16x8 a, s16x8 b, f32x4 c) {
    return __builtin_amdgcn_mfma_f32_16x16x32_bf16(a, b, c, 0, 0, 0);
}
// async global->LDS, 16B per lane; LDS dest = wave-uniform base + lane*16
__device__ __forceinline__ void gload16(const u16* g, u16* l) {
    __builtin_amdgcn_global_load_lds(
        (const __attribute__((address_space(1))) void*)g,
        (__attribute__((address_space(3))) void*)l, 16, 0, 0);
}

// ---------------- converts / transposes ----------------

// both f32->bf16 converts in one launch (4096 blocks; first half x, second sym)
__global__ void cvt2_f32_bf16(const float* __restrict__ a, const float* __restrict__ b,
                              u16* __restrict__ oa, u16* __restrict__ ob) {
    int i = (blockIdx.x * 256 + threadIdx.x) * 8;
    const int half = (i >= 4194304) ? 1 : 0;
    const float* in = half ? b : a;
    u16* out = half ? ob : oa;
    int off = i - half * 4194304;
    float4 x = *(const float4*)(in + off);
    float4 y = *(const float4*)(in + off + 4);
    s16x8 o;
    o[0] = (short)f2bf(x.x); o[1] = (short)f2bf(x.y);
    o[2] = (short)f2bf(x.z); o[3] = (short)f2bf(x.w);
    o[4] = (short)f2bf(y.x); o[5] = (short)f2bf(y.y);
    o[6] = (short)f2bf(y.z); o[7] = (short)f2bf(y.w);
    *(s16x8*)(out + off) = o;
}

struct WP { const float* p[10]; };

__global__ void transpose_w(WP wp, u16* __restrict__ WcatT,
                            u16* __restrict__ woSaT, u16* __restrict__ woRaT) {
    const int z = blockIdx.z;
    const float* W;
    u16* Wt;
    int K;
    if (z < 8) { W = wp.p[z]; Wt = WcatT + (size_t)z * 524288; K = 1024; }
    else       { W = wp.p[z]; Wt = (z == 8) ? woSaT : woRaT;   K = 512;  }
    const int N = 512;
    const int kt = blockIdx.x * 32, nt = blockIdx.y * 32;
    if (kt >= K) return;
    __shared__ float t[32][33];
    const int c = threadIdx.x & 31, r0 = threadIdx.x >> 5;
#pragma unroll
    for (int it = 0; it < 4; ++it) {
        int r = it * 8 + r0;
        t[r][c] = W[(size_t)(kt + r) * N + nt + c];
    }
    __syncthreads();
#pragma unroll
    for (int it = 0; it < 4; ++it) {
        int r = it * 8 + r0;
        Wt[(size_t)(nt + r) * K + kt + c] = f2bf(t[c][r]);
    }
}

// Vt[b][hd][s'] with s' kappa-permuted within each 32-group so the PV
// B-fragment is ONE contiguous s16x8 per lane:
// old within-32 j -> new = (j&15)/4*8 + (j>>4)*4 + (j&3)
__global__ void transpose_v2(const u16* __restrict__ P, u16* __restrict__ Vt, int colOff) {
    const int st = blockIdx.x * 32, ht = blockIdx.y * 32, b = blockIdx.z;
    __shared__ u16 t[32][34];
    const int c = threadIdx.x & 31, r0 = threadIdx.x >> 5;
#pragma unroll
    for (int it = 0; it < 4; ++it) {
        int r = it * 8 + r0;
        t[r][c] = P[(size_t)(b * 1024 + st + r) * LDP + colOff + ht + c];
    }
    __syncthreads();
    const int cp = ((c & 15) >> 2) * 8 + (c >> 4) * 4 + (c & 3);
#pragma unroll
    for (int it = 0; it < 4; ++it) {
        int r = it * 8 + r0;
        Vt[(size_t)b * 524288 + (size_t)(ht + r) * 1024 + st + cp] = t[c][r];
    }
}

// ---------------- RoPE (standalone, in-place on QSA,KSA,QA,KA regions) --------

__global__ void rope_kernel(u16* __restrict__ P, const float* __restrict__ fcos,
                            const float* __restrict__ fsin) {
    int idx = blockIdx.x * 256 + threadIdx.x;
    int row = idx >> 10;
    int rem = idx & 1023;
    int region = rem >> 8;
    int pr = rem & 255;
    int head = pr >> 5, p = pr & 31;
    int off = (region + (region >> 1)) * 512;
    int col = off + head * 64 + 2 * p;
    int s = row & 1023;
    float c = fcos[s * 32 + p], sn = fsin[s * 32 + p];
    u32* ptr = (u32*)(P + (size_t)row * LDP + col);
    u32 v = *ptr;
    float xr = bf2f((u16)(v & 0xffff)), xi = bf2f((u16)(v >> 16));
    u16 o0 = f2bf(xr * c - xi * sn);
    u16 o1 = f2bf(xr * sn + xi * c);
    *ptr = (u32)o0 | ((u32)o1 << 16);
}

// ---------------- GEMM: BK=64, T2 both-sides XOR swizzle, 2-D XCD chunks ------

template<bool OUT_BF16, bool SWZ>
__global__ __launch_bounds__(256) void gemm_bf16(
    const u16* __restrict__ A, const u16* __restrict__ A2, int lda, int nswitch,
    const u16* __restrict__ Bt, int ldb,
    void* __restrict__ Cp, int ldc, int ccolOff, int K)
{
    __shared__ u16 As[128][64];
    __shared__ u16 Bs[128][64];
    const int tid = threadIdx.x;
    int bx = blockIdx.x, by = blockIdx.y;
    if (SWZ) {
        int lin = by * gridDim.x + bx;
        int k = lin & 7, j = lin >> 3;
        bx = (k & 3) * 8 + (j & 7);
        by = (k >> 2) * 16 + (j >> 3);
    }
    const int m0 = bx * 128, n0 = by * 128;
    const u16* Ause = (A2 != nullptr && n0 >= nswitch) ? A2 : A;
    const int w = tid >> 6, lane = tid & 63;
    const int w32 = w * 32;
    const int wm = (w >> 1) * 64, wn = (w & 1) * 64;
    const int lr = lane & 15, lg = lane >> 4;
    const int srow = lane >> 3;
    const int sc16 = ((lane & 7) ^ srow) * 8;
    f32x4 acc[4][4] = {};

    for (int k0 = 0; k0 < K; k0 += 64) {
        const u16* ga = &Ause[(size_t)(m0 + w32 + srow) * lda + k0 + sc16];
        const u16* gb = &Bt [(size_t)(n0 + w32 + srow) * ldb + k0 + sc16];
        gload16(ga,            &As[w32][0]);
        gload16(ga +  8 * lda, &As[w32 +  8][0]);
        gload16(ga + 16 * lda, &As[w32 + 16][0]);
        gload16(ga + 24 * lda, &As[w32 + 24][0]);
        gload16(gb,            &Bs[w32][0]);
        gload16(gb +  8 * ldb, &Bs[w32 +  8][0]);
        gload16(gb + 16 * ldb, &Bs[w32 + 16][0]);
        gload16(gb + 24 * ldb, &Bs[w32 + 24][0]);
        __syncthreads();
#pragma unroll
        for (int kk = 0; kk < 2; ++kk) {
            s16x8 af[4], bfr[4];
#pragma unroll
            for (int t = 0; t < 4; ++t) {
                const int ca = (((kk * 4 + lg) ^ (lr & 7)) * 8);
                af[t]  = *(const s16x8*)&As[wm + t * 16 + lr][ca];
                bfr[t] = *(const s16x8*)&Bs[wn + t * 16 + lr][ca];
            }
#pragma unroll
            for (int i = 0; i < 4; ++i)
#pragma unroll
                for (int j = 0; j < 4; ++j)
                    acc[i][j] = mfma16(af[i], bfr[j], acc[i][j]);
        }
        __syncthreads();
    }
#pragma unroll
    for (int i = 0; i < 4; ++i)
#pragma unroll
        for (int j = 0; j < 4; ++j)
#pragma unroll
            for (int r = 0; r < 4; ++r) {
                int row = m0 + wm + i * 16 + lg * 4 + r;
                int col = n0 + wn + j * 16 + lr;
                float val = acc[i][j][r];
                if (OUT_BF16)
                    ((u16*)Cp)[(size_t)row * ldc + ccolOff + col] = f2bf(val);
                else
                    ((float*)Cp)[(size_t)row * ldc + ccolOff + col] = val;
            }
}

// ---------------- SA attention (R9/R13): unstabilized softmax, 1-wave blocks --

__global__ __launch_bounds__(64) void attn_sa(u16* __restrict__ P, const u16* __restrict__ Vt) {
    const int bid = blockIdx.x;
    const int h = bid & 7;
    const int b = (bid >> 3) & 3;
    const int pr = bid >> 5;
    const int xt1 = pr, xt2 = 63 - pr;
    const int lane = threadIdx.x, lr = lane & 15, lg = lane >> 4;
    const size_t rowBase = (size_t)b * 1024;
    const int i0_1 = xt1 * 16, i0_2 = xt2 * 16;
    const int ir1 = i0_1 + lr, ir2 = i0_2 + lr;

    const u16* Kbase = P + rowBase * LDP + (C_KSA + h * 64);
    const u16* Vb = Vt + ((size_t)(b * 8 + h)) * 65536;

    s16x8 q1[2], q2[2];
    {
        const u16* q = P + (rowBase + ir1) * LDP + (C_QSA + h * 64) + lg * 8;
        q1[0] = *(const s16x8*)q; q1[1] = *(const s16x8*)(q + 32);
        q = P + (rowBase + ir2) * LDP + (C_QSA + h * 64) + lg * 8;
        q2[0] = *(const s16x8*)q; q2[1] = *(const s16x8*)(q + 32);
    }
    f32x4 o1[4] = {}, o2[4] = {};
    float l1 = 0.f, l2 = 0.f;
    const int njt  = (xt2 >> 1) + 1;
    const int njt1 = (xt1 >> 1) + 1;

    for (int jt = 0; jt < njt; ++jt) {
        const int j0 = jt * 32;
        const bool act1 = (jt < njt1);
        s16x8 kf[2][2], vfr[4];
#pragma unroll
        for (int sub = 0; sub < 2; ++sub) {
            const u16* kp = Kbase + (size_t)(j0 + sub * 16 + lr) * LDP + lg * 8;
            kf[sub][0] = *(const s16x8*)kp;
            kf[sub][1] = *(const s16x8*)(kp + 32);
        }
#pragma unroll
        for (int ds = 0; ds < 4; ++ds)
            vfr[ds] = *(const s16x8*)(Vb + (size_t)(ds * 16 + lr) * 1024 + j0 + 8 * lg);

        f32x4 sc2[2] = {{0.f,0.f,0.f,0.f},{0.f,0.f,0.f,0.f}};
        f32x4 sc1[2] = {{0.f,0.f,0.f,0.f},{0.f,0.f,0.f,0.f}};
#pragma unroll
        for (int sub = 0; sub < 2; ++sub) {
            sc2[sub] = mfma16(kf[sub][0], q2[0], sc2[sub]);
            sc2[sub] = mfma16(kf[sub][1], q2[1], sc2[sub]);
        }
        if (act1) {
#pragma unroll
            for (int sub = 0; sub < 2; ++sub) {
                sc1[sub] = mfma16(kf[sub][0], q1[0], sc1[sub]);
                sc1[sub] = mfma16(kf[sub][1], q1[1], sc1[sub]);
            }
        }
        s16x8 pa;
#pragma unroll
        for (int sub = 0; sub < 2; ++sub)
#pragma unroll
            for (int r = 0; r < 4; ++r) {
                int j = j0 + sub * 16 + 4 * lg + r;
                float p = (j <= ir2) ? fexp(sc2[sub][r] * 0.125f) : 0.f;
                l2 += p;
                pa[sub * 4 + r] = (short)f2bf(p);
            }
#pragma unroll
        for (int ds = 0; ds < 4; ++ds) o2[ds] = mfma16(pa, vfr[ds], o2[ds]);
        if (act1) {
#pragma unroll
            for (int sub = 0; sub < 2; ++sub)
#pragma unroll
                for (int r = 0; r < 4; ++r) {
                    int j = j0 + sub * 16 + 4 * lg + r;
                    float p = (j <= ir1) ? fexp(sc1[sub][r] * 0.125f) : 0.f;
                    l1 += p;
                    pa[sub * 4 + r] = (short)f2bf(p);
                }
#pragma unroll
            for (int ds = 0; ds < 4; ++ds) o1[ds] = mfma16(pa, vfr[ds], o1[ds]);
        }
    }
    l1 += __shfl_xor(l1, 16); l1 += __shfl_xor(l1, 32);
    l2 += __shfl_xor(l2, 16); l2 += __shfl_xor(l2, 32);
    float li1[4], li2[4];
#pragma unroll
    for (int r = 0; r < 4; ++r) {
        li1[r] = 1.f / __shfl(l1, 4 * lg + r);
        li2[r] = 1.f / __shfl(l2, 4 * lg + r);
    }
#pragma unroll
    for (int ds = 0; ds < 4; ++ds)
#pragma unroll
        for (int r = 0; r < 4; ++r) {
            P[(rowBase + i0_1 + 4 * lg + r) * LDP + (C_QSA + h * 64) + ds * 16 + lr] =
                f2bf(o1[ds][r] * li1[r]);
            P[(rowBase + i0_2 + 4 * lg + r) * LDP + (C_QSA + h * 64) + ds * 16 + lr] =
                f2bf(o2[ds][r] * li2[r]);
        }
}

// ---------------- RA attention v5 (R13): unstabilized softmax, 1 barrier/64j --
// 512 blocks x 512 thr. bid&7 = (s,b) XCD slot (parity s), xt = 63-(bid>>3).
// Wave w: head w, rel channel w. Per iter: j-tiles {jt, jt+2}, relT
// double-buffered -> ONE barrier. No max/rescale anywhere.
// Writes RAW partials (l, o, rm); merge_ra combines parity splits.

__global__ __launch_bounds__(512) void attn_ra(u16* __restrict__ P, const u16* __restrict__ SVt,
                                               float* __restrict__ opart,
                                               float* __restrict__ mlr) {
    const int bid = blockIdx.x;
    const int slot = bid & 7;
    const int b = slot & 3, s = slot >> 2;
    const int xt = 63 - (bid >> 3);
    const int w = threadIdx.x >> 6, lane = threadIdx.x & 63;
    const int lr = lane & 15, lg = lane >> 4;
    const int h = w;
    const size_t rowBase = (size_t)b * 1024;
    const int i0 = xt * 16;
    const int ir = i0 + lr;

    __shared__ float relT[2][2][32][16][8];   // [dbuf][tileAB][j-local][i][swz slot]

    const u16* Kbase  = P + rowBase * LDP + (C_KA + h * 64);
    const u16* KRbase = P + rowBase * LDP + (C_KR + h * 64);
    const u16* Vb = SVt + ((size_t)(b * 8 + h)) * 65536;

    s16x8 qf[2], qrf[2];
    {
        const u16* q = P + (rowBase + ir) * LDP + (C_QA + h * 64) + lg * 8;
        qf[0] = *(const s16x8*)q; qf[1] = *(const s16x8*)(q + 32);
        const u16* qr = P + (rowBase + ir) * LDP + (C_QR + h * 64) + lg * 8;
        qrf[0] = *(const s16x8*)qr; qrf[1] = *(const s16x8*)(qr + 32);
    }
    f32x4 o[4] = {};
    float rmr[8] = {};                      // rotated slots: slot k = channel (k-lr)&7
    float l = 0.f;
    const int njt = (xt >> 1) + 1;
    const int cnt = (njt - s + 1) >> 1;     // tiles of parity s
    const int npair = (cnt + 1) >> 1;
    const int slotw = (w + lr) & 7;

    for (int u = 0; u < npair; ++u) {
        const int j0a = (s + 4 * u) * 32;
        const bool actB = (2 * u + 1) < cnt;        // block-uniform
        const int j0b = actB ? j0a + 64 : j0a;      // clamp for safe loads
        // ---- K / K_rel / V loads ----
        s16x8 kfA[2][2], krA[2][2], kfB[2][2], krB[2][2], vfA[4], vfB[4];
#pragma unroll
        for (int sub = 0; sub < 2; ++sub) {
            const u16* kp = Kbase + (size_t)(j0a + sub * 16 + lr) * LDP + lg * 8;
            kfA[sub][0] = *(const s16x8*)kp;  kfA[sub][1] = *(const s16x8*)(kp + 32);
            const u16* krp = KRbase + (size_t)(j0a + sub * 16 + lr) * LDP + lg * 8;
            krA[sub][0] = *(const s16x8*)krp; krA[sub][1] = *(const s16x8*)(krp + 32);
            kp = Kbase + (size_t)(j0b + sub * 16 + lr) * LDP + lg * 8;
            kfB[sub][0] = *(const s16x8*)kp;  kfB[sub][1] = *(const s16x8*)(kp + 32);
            krp = KRbase + (size_t)(j0b + sub * 16 + lr) * LDP + lg * 8;
            krB[sub][0] = *(const s16x8*)krp; krB[sub][1] = *(const s16x8*)(krp + 32);
        }
#pragma unroll
        for (int ds = 0; ds < 4; ++ds) {
            vfA[ds] = *(const s16x8*)(Vb + (size_t)(ds * 16 + lr) * 1024 + j0a + 8 * lg);
            vfB[ds] = *(const s16x8*)(Vb + (size_t)(ds * 16 + lr) * 1024 + j0b + 8 * lg);
        }
        // ---- MFMAs ----
        f32x4 scA[2] = {{0.f,0.f,0.f,0.f},{0.f,0.f,0.f,0.f}};
        f32x4 scB[2] = {{0.f,0.f,0.f,0.f},{0.f,0.f,0.f,0.f}};
        f32x4 rtA[2] = {{0.f,0.f,0.f,0.f},{0.f,0.f,0.f,0.f}};
        f32x4 rtB[2] = {{0.f,0.f,0.f,0.f},{0.f,0.f,0.f,0.f}};
#pragma unroll
        for (int sub = 0; sub < 2; ++sub) {
            scA[sub] = mfma16(kfA[sub][0], qf[0], scA[sub]);
            scA[sub] = mfma16(kfA[sub][1], qf[1], scA[sub]);
            rtA[sub] = mfma16(krA[sub][0], qrf[0], rtA[sub]);
            rtA[sub] = mfma16(krA[sub][1], qrf[1], rtA[sub]);
            scB[sub] = mfma16(kfB[sub][0], qf[0], scB[sub]);
            scB[sub] = mfma16(kfB[sub][1], qf[1], scB[sub]);
            rtB[sub] = mfma16(krB[sub][0], qrf[0], rtB[sub]);
            rtB[sub] = mfma16(krB[sub][1], qrf[1], rtB[sub]);
        }
        // ---- p = exp(s) (no max), accumulate l, pack ----
        float pA[2][4], pB[2][4];
#pragma unroll
        for (int sub = 0; sub < 2; ++sub)
#pragma unroll
            for (int r = 0; r < 4; ++r) {
                int jA = j0a + sub * 16 + 4 * lg + r;
                int jB = j0b + sub * 16 + 4 * lg + r;
                pA[sub][r] = (jA <= ir) ? fexp(scA[sub][r] * 0.125f) : 0.f;
                pB[sub][r] = (actB && jB <= ir) ? fexp(scB[sub][r] * 0.125f) : 0.f;
                l += pA[sub][r] + pB[sub][r];
            }
        // ---- publish tanh(rel) (double-buffered), ONE barrier ----
#pragma unroll
        for (int sub = 0; sub < 2; ++sub)
#pragma unroll
            for (int r = 0; r < 4; ++r) {
                int jp = sub * 16 + 4 * lg + r;
                relT[u & 1][0][jp][lr][slotw] = ftanh(rtA[sub][r] * 0.125f);
                relT[u & 1][1][jp][lr][slotw] = ftanh(rtB[sub][r] * 0.125f);
            }
        __syncthreads();
        // ---- accumulate p * rel, all 8 slots, both tiles ----
#pragma unroll
        for (int sub = 0; sub < 2; ++sub)
#pragma unroll
            for (int r = 0; r < 4; ++r) {
                int jp = sub * 16 + 4 * lg + r;
                f32x4 a  = *(const f32x4*)&relT[u & 1][0][jp][lr][0];
                f32x4 bb = *(const f32x4*)&relT[u & 1][0][jp][lr][4];
                float pv = pA[sub][r];
#pragma unroll
                for (int k = 0; k < 4; ++k) {
                    rmr[k]     += pv * a[k];
                    rmr[4 + k] += pv * bb[k];
                }
                a  = *(const f32x4*)&relT[u & 1][1][jp][lr][0];
                bb = *(const f32x4*)&relT[u & 1][1][jp][lr][4];
                pv = pB[sub][r];
#pragma unroll
                for (int k = 0; k < 4; ++k) {
                    rmr[k]     += pv * a[k];
                    rmr[4 + k] += pv * bb[k];
                }
            }
        // ---- PV (no rescale) ----
        s16x8 paA, paB;
#pragma unroll
        for (int r = 0; r < 4; ++r) {
            paA[r]     = (short)f2bf(pA[0][r]);
            paA[4 + r] = (short)f2bf(pA[1][r]);
            paB[r]     = (short)f2bf(pB[0][r]);
            paB[4 + r] = (short)f2bf(pB[1][r]);
        }
#pragma unroll
        for (int ds = 0; ds < 4; ++ds) {
            o[ds] = mfma16(paA, vfA[ds], o[ds]);
            o[ds] = mfma16(paB, vfB[ds], o[ds]);
        }
    }

    // ---- epilogue: reduce l and rotated slots, un-rotate, write partials ----
    l += __shfl_xor(l, 16); l += __shfl_xor(l, 32);
#pragma unroll
    for (int k = 0; k < 8; ++k) {
        float v = rmr[k];
        v += __shfl_xor(v, 16);
        v += __shfl_xor(v, 32);
        rmr[k] = v;
    }
    float g[8], t0[8];
    const int t = lr & 7;
#pragma unroll
    for (int k = 0; k < 8; ++k) g[k] = rmr[k];
#pragma unroll
    for (int k = 0; k < 8; ++k) t0[k] = (t & 1) ? g[(k + 1) & 7] : g[k];
#pragma unroll
    for (int k = 0; k < 8; ++k) g[k]  = (t & 2) ? t0[(k + 2) & 7] : t0[k];
#pragma unroll
    for (int k = 0; k < 8; ++k) t0[k] = (t & 4) ? g[(k + 4) & 7] : g[k];

    const int headRow = (b * 8 + h) * 1024;
#pragma unroll
    for (int ds = 0; ds < 4; ++ds)
#pragma unroll
        for (int r = 0; r < 4; ++r) {
            int row = headRow + i0 + 4 * lg + r;
            opart[((size_t)row * 2 + s) * 64 + ds * 16 + lr] = o[ds][r];
        }
    if (lg == 0) {
        float* pm = &mlr[((size_t)(headRow + i0 + lr) * 2 + s) * 10];
        pm[0] = l;
#pragma unroll
        for (int c = 0; c < 8; ++c) pm[1 + c] = t0[c];
    }
}

// ---------------- RA merge: (o0+o1)/(l0+l1), wr projection, write Pcat --------

__global__ __launch_bounds__(256) void merge_ra(const float* __restrict__ opart,
                                                const float* __restrict__ mlr,
                                                const float* __restrict__ wr,
                                                u16* __restrict__ P) {
    const int gid = blockIdx.x * 4 + (threadIdx.x >> 6);   // [0, 32768)
    const int d = threadIdx.x & 63;
    const int i = gid & 1023;
    const int h = (gid >> 10) & 7;
    const int b = gid >> 13;
    const float* ml0 = &mlr[(size_t)gid * 20];
    const float* ml1 = ml0 + 10;
    float ilt = 1.f / (ml0[0] + ml1[0]);
    float acc = (opart[(size_t)gid * 128 + d] +
                 opart[(size_t)gid * 128 + 64 + d]) * ilt;
#pragma unroll
    for (int c = 0; c < 8; ++c) {
        float rm = (ml0[1 + c] + ml1[1 + c]) * ilt;
        acc += rm * wr[h * 512 + d * 8 + c];
    }
    P[((size_t)(b * 1024 + i)) * LDP + C_QA + h * 64 + d] = f2bf(acc);
}

// ---------------- launcher ----------------

extern "C" void kernel_launch(void* const* d_in, const int* in_sizes, int n_in,
                              void* d_out, int out_size, void* d_ws, size_t ws_size,
                              hipStream_t stream)
{
    const float* x     = (const float*)d_in[0];
    const float* sym   = (const float*)d_in[1];
    const float* fcos  = (const float*)d_in[2];
    const float* fsin  = (const float*)d_in[3];
    const float* w_qsa = (const float*)d_in[4];
    const float* w_ksa = (const float*)d_in[5];
    const float* w_vsa = (const float*)d_in[6];
    const float* w_osa = (const float*)d_in[7];
    const float* w_qa  = (const float*)d_in[8];
    const float* w_ka  = (const float*)d_in[9];
    const float* w_qr  = (const float*)d_in[10];
    const float* w_kr  = (const float*)d_in[11];
    const float* wr    = (const float*)d_in[12];
    const float* w_sv  = (const float*)d_in[13];
    const float* w_ora = (const float*)d_in[14];

    char* ws = (char*)d_ws;
    u16* xb    = (u16*)(ws);                                  // 8 MB   (dead after proj GEMM)
    u16* symb  = (u16*)(ws + (8u  << 20));                    // 8 MB   (dead after proj GEMM)
    u16* WcatT = (u16*)(ws + (16u << 20));                    // 8 MB   (dead after proj GEMM)
    u16* woSaT = (u16*)(ws + (24u << 20));                    // 512 KB
    u16* woRaT = (u16*)(ws + (24u << 20) + (512u << 10));     // 512 KB
    u16* Pcat  = (u16*)(ws + (25u << 20));                    // 32 MB
    u16* vT    = (u16*)(ws + (57u << 20));                    // 4 MB
    u16* svT   = (u16*)(ws + (61u << 20));                    // 4 MB
    // RA partials reuse the dead 0..24 MB region after the projection GEMM:
    float* opart = (float*)(ws);                              // 16.78 MB
    float* mlrp  = (float*)(ws + (17u << 20));                // 2.62 MB

    cvt2_f32_bf16<<<4096, 256, 0, stream>>>(x, sym, xb, symb);

    WP wp{{w_qsa, w_ksa, w_vsa, w_qa, w_ka, w_qr, w_kr, w_sv, w_osa, w_ora}};
    transpose_w<<<dim3(32, 16, 10), 256, 0, stream>>>(wp, WcatT, woSaT, woRaT);

    gemm_bf16<true, true><<<dim3(32, 32), 256, 0, stream>>>(
        xb, symb, 1024, C_SV, WcatT, 1024, Pcat, LDP, 0, 1024);

    rope_kernel<<<16384, 256, 0, stream>>>(Pcat, fcos, fsin);

    transpose_v2<<<dim3(32, 16, 4), 256, 0, stream>>>(Pcat, vT,  C_VSA);
    transpose_v2<<<dim3(32, 16, 4), 256, 0, stream>>>(Pcat, svT, C_SV);

    attn_sa<<<1024, 64, 0, stream>>>(Pcat, vT);
    attn_ra<<<512, 512, 0, stream>>>(Pcat, svT, opart, mlrp);
    merge_ra<<<8192, 256, 0, stream>>>(opart, mlrp, wr, Pcat);

    // merged output projection: cols [0,512) = wo_sa @ sa_out, [512,1024) = wo_ra @ ra_out
    gemm_bf16<false, false><<<dim3(32, 8), 256, 0, stream>>>(
        Pcat + C_QSA, Pcat + C_QA, LDP, 512, woSaT, 512, d_out, 1024, 0, 512);
}

// Round 20
// 201.258 us; speedup vs baseline: 2.1218x; 1.0073x over previous
//
#include <hip/hip_runtime.h>

typedef unsigned short u16;
typedef unsigned int u32;
typedef __attribute__((ext_vector_type(8))) short s16x8;
typedef __attribute__((ext_vector_type(4))) float f32x4;

// Pcat column offsets (bf16 projection buffer, 4096 rows x 4096 cols)
#define C_QSA 0
#define C_KSA 512
#define C_VSA 1024
#define C_QA  1536
#define C_KA  2048
#define C_QR  2560
#define C_KR  3072
#define C_SV  3584
#define LDP   4096

__device__ __forceinline__ u16 f2bf(float f) {
    union { float f; unsigned u; } v; v.f = f;
    return (u16)((v.u + 0x7FFFu + ((v.u >> 16) & 1u)) >> 16);  // RNE
}
__device__ __forceinline__ float bf2f(u16 h) {
    union { unsigned u; float f; } v; v.u = ((unsigned)h) << 16; return v.f;
}
__device__ __forceinline__ float fexp(float y) {
    return __builtin_exp2f(y * 1.4426950408889634f);
}
__device__ __forceinline__ float ftanh(float x) {
    float e = __builtin_exp2f(x * 2.885390081777927f);    // exp(2x)
    return 1.f - 2.f / (e + 1.f);
}
__device__ __forceinline__ f32x4 mfma16(s16x8 a, s16x8 b, f32x4 c) {
    return __builtin_amdgcn_mfma_f32_16x16x32_bf16(a, b, c, 0, 0, 0);
}
// async global->LDS, 16B per lane; LDS dest = wave-uniform base + lane*16
__device__ __forceinline__ void gload16(const u16* g, u16* l) {
    __builtin_amdgcn_global_load_lds(
        (const __attribute__((address_space(1))) void*)g,
        (__attribute__((address_space(3))) void*)l, 16, 0, 0);
}

// ---------------- converts / transposes ----------------

// both f32->bf16 converts in one launch (4096 blocks; first half x, second sym)
__global__ void cvt2_f32_bf16(const float* __restrict__ a, const float* __restrict__ b,
                              u16* __restrict__ oa, u16* __restrict__ ob) {
    int i = (blockIdx.x * 256 + threadIdx.x) * 8;
    const int half = (i >= 4194304) ? 1 : 0;
    const float* in = half ? b : a;
    u16* out = half ? ob : oa;
    int off = i - half * 4194304;
    float4 x = *(const float4*)(in + off);
    float4 y = *(const float4*)(in + off + 4);
    s16x8 o;
    o[0] = (short)f2bf(x.x); o[1] = (short)f2bf(x.y);
    o[2] = (short)f2bf(x.z); o[3] = (short)f2bf(x.w);
    o[4] = (short)f2bf(y.x); o[5] = (short)f2bf(y.y);
    o[6] = (short)f2bf(y.z); o[7] = (short)f2bf(y.w);
    *(s16x8*)(out + off) = o;
}

struct WP { const float* p[10]; };

__global__ void transpose_w(WP wp, u16* __restrict__ WcatT,
                            u16* __restrict__ woSaT, u16* __restrict__ woRaT) {
    const int z = blockIdx.z;
    const float* W;
    u16* Wt;
    int K;
    if (z < 8) { W = wp.p[z]; Wt = WcatT + (size_t)z * 524288; K = 1024; }
    else       { W = wp.p[z]; Wt = (z == 8) ? woSaT : woRaT;   K = 512;  }
    const int N = 512;
    const int kt = blockIdx.x * 32, nt = blockIdx.y * 32;
    if (kt >= K) return;
    __shared__ float t[32][33];
    const int c = threadIdx.x & 31, r0 = threadIdx.x >> 5;
#pragma unroll
    for (int it = 0; it < 4; ++it) {
        int r = it * 8 + r0;
        t[r][c] = W[(size_t)(kt + r) * N + nt + c];
    }
    __syncthreads();
#pragma unroll
    for (int it = 0; it < 4; ++it) {
        int r = it * 8 + r0;
        Wt[(size_t)(nt + r) * K + kt + c] = f2bf(t[c][r]);
    }
}

// Vt[b][hd][s'] with s' kappa-permuted within each 32-group so the PV
// B-fragment is ONE contiguous s16x8 per lane:
// old within-32 j -> new = (j&15)/4*8 + (j>>4)*4 + (j&3)
__global__ void transpose_v2(const u16* __restrict__ P, u16* __restrict__ Vt, int colOff) {
    const int st = blockIdx.x * 32, ht = blockIdx.y * 32, b = blockIdx.z;
    __shared__ u16 t[32][34];
    const int c = threadIdx.x & 31, r0 = threadIdx.x >> 5;
#pragma unroll
    for (int it = 0; it < 4; ++it) {
        int r = it * 8 + r0;
        t[r][c] = P[(size_t)(b * 1024 + st + r) * LDP + colOff + ht + c];
    }
    __syncthreads();
    const int cp = ((c & 15) >> 2) * 8 + (c >> 4) * 4 + (c & 3);
#pragma unroll
    for (int it = 0; it < 4; ++it) {
        int r = it * 8 + r0;
        Vt[(size_t)b * 524288 + (size_t)(ht + r) * 1024 + st + cp] = t[c][r];
    }
}

// ---------------- RoPE (standalone, in-place on QSA,KSA,QA,KA regions) --------

__global__ void rope_kernel(u16* __restrict__ P, const float* __restrict__ fcos,
                            const float* __restrict__ fsin) {
    int idx = blockIdx.x * 256 + threadIdx.x;
    int row = idx >> 10;
    int rem = idx & 1023;
    int region = rem >> 8;
    int pr = rem & 255;
    int head = pr >> 5, p = pr & 31;
    int off = (region + (region >> 1)) * 512;
    int col = off + head * 64 + 2 * p;
    int s = row & 1023;
    float c = fcos[s * 32 + p], sn = fsin[s * 32 + p];
    u32* ptr = (u32*)(P + (size_t)row * LDP + col);
    u32 v = *ptr;
    float xr = bf2f((u16)(v & 0xffff)), xi = bf2f((u16)(v >> 16));
    u16 o0 = f2bf(xr * c - xi * sn);
    u16 o1 = f2bf(xr * sn + xi * c);
    *ptr = (u32)o0 | ((u32)o1 << 16);
}

// ---------------- GEMM: BK=64, T2 both-sides XOR swizzle, 2-D XCD chunks ------

template<bool OUT_BF16, bool SWZ>
__global__ __launch_bounds__(256) void gemm_bf16(
    const u16* __restrict__ A, const u16* __restrict__ A2, int lda, int nswitch,
    const u16* __restrict__ Bt, int ldb,
    void* __restrict__ Cp, int ldc, int ccolOff, int K)
{
    __shared__ u16 As[128][64];
    __shared__ u16 Bs[128][64];
    const int tid = threadIdx.x;
    int bx = blockIdx.x, by = blockIdx.y;
    if (SWZ) {
        int lin = by * gridDim.x + bx;
        int k = lin & 7, j = lin >> 3;
        bx = (k & 3) * 8 + (j & 7);
        by = (k >> 2) * 16 + (j >> 3);
    }
    const int m0 = bx * 128, n0 = by * 128;
    const u16* Ause = (A2 != nullptr && n0 >= nswitch) ? A2 : A;
    const int w = tid >> 6, lane = tid & 63;
    const int w32 = w * 32;
    const int wm = (w >> 1) * 64, wn = (w & 1) * 64;
    const int lr = lane & 15, lg = lane >> 4;
    const int srow = lane >> 3;
    const int sc16 = ((lane & 7) ^ srow) * 8;
    f32x4 acc[4][4] = {};

    for (int k0 = 0; k0 < K; k0 += 64) {
        const u16* ga = &Ause[(size_t)(m0 + w32 + srow) * lda + k0 + sc16];
        const u16* gb = &Bt [(size_t)(n0 + w32 + srow) * ldb + k0 + sc16];
        gload16(ga,            &As[w32][0]);
        gload16(ga +  8 * lda, &As[w32 +  8][0]);
        gload16(ga + 16 * lda, &As[w32 + 16][0]);
        gload16(ga + 24 * lda, &As[w32 + 24][0]);
        gload16(gb,            &Bs[w32][0]);
        gload16(gb +  8 * ldb, &Bs[w32 +  8][0]);
        gload16(gb + 16 * ldb, &Bs[w32 + 16][0]);
        gload16(gb + 24 * ldb, &Bs[w32 + 24][0]);
        __syncthreads();
#pragma unroll
        for (int kk = 0; kk < 2; ++kk) {
            s16x8 af[4], bfr[4];
#pragma unroll
            for (int t = 0; t < 4; ++t) {
                const int ca = (((kk * 4 + lg) ^ (lr & 7)) * 8);
                af[t]  = *(const s16x8*)&As[wm + t * 16 + lr][ca];
                bfr[t] = *(const s16x8*)&Bs[wn + t * 16 + lr][ca];
            }
#pragma unroll
            for (int i = 0; i < 4; ++i)
#pragma unroll
                for (int j = 0; j < 4; ++j)
                    acc[i][j] = mfma16(af[i], bfr[j], acc[i][j]);
        }
        __syncthreads();
    }
#pragma unroll
    for (int i = 0; i < 4; ++i)
#pragma unroll
        for (int j = 0; j < 4; ++j)
#pragma unroll
            for (int r = 0; r < 4; ++r) {
                int row = m0 + wm + i * 16 + lg * 4 + r;
                int col = n0 + wn + j * 16 + lr;
                float val = acc[i][j][r];
                if (OUT_BF16)
                    ((u16*)Cp)[(size_t)row * ldc + ccolOff + col] = f2bf(val);
                else
                    ((float*)Cp)[(size_t)row * ldc + ccolOff + col] = val;
            }
}

// ---------------- SA attention (R13 + T5 setprio on MFMA clusters) ------------

__global__ __launch_bounds__(64) void attn_sa(u16* __restrict__ P, const u16* __restrict__ Vt) {
    const int bid = blockIdx.x;
    const int h = bid & 7;
    const int b = (bid >> 3) & 3;
    const int pr = bid >> 5;
    const int xt1 = pr, xt2 = 63 - pr;
    const int lane = threadIdx.x, lr = lane & 15, lg = lane >> 4;
    const size_t rowBase = (size_t)b * 1024;
    const int i0_1 = xt1 * 16, i0_2 = xt2 * 16;
    const int ir1 = i0_1 + lr, ir2 = i0_2 + lr;

    const u16* Kbase = P + rowBase * LDP + (C_KSA + h * 64);
    const u16* Vb = Vt + ((size_t)(b * 8 + h)) * 65536;

    s16x8 q1[2], q2[2];
    {
        const u16* q = P + (rowBase + ir1) * LDP + (C_QSA + h * 64) + lg * 8;
        q1[0] = *(const s16x8*)q; q1[1] = *(const s16x8*)(q + 32);
        q = P + (rowBase + ir2) * LDP + (C_QSA + h * 64) + lg * 8;
        q2[0] = *(const s16x8*)q; q2[1] = *(const s16x8*)(q + 32);
    }
    f32x4 o1[4] = {}, o2[4] = {};
    float l1 = 0.f, l2 = 0.f;
    const int njt  = (xt2 >> 1) + 1;
    const int njt1 = (xt1 >> 1) + 1;

    for (int jt = 0; jt < njt; ++jt) {
        const int j0 = jt * 32;
        const bool act1 = (jt < njt1);
        s16x8 kf[2][2], vfr[4];
#pragma unroll
        for (int sub = 0; sub < 2; ++sub) {
            const u16* kp = Kbase + (size_t)(j0 + sub * 16 + lr) * LDP + lg * 8;
            kf[sub][0] = *(const s16x8*)kp;
            kf[sub][1] = *(const s16x8*)(kp + 32);
        }
#pragma unroll
        for (int ds = 0; ds < 4; ++ds)
            vfr[ds] = *(const s16x8*)(Vb + (size_t)(ds * 16 + lr) * 1024 + j0 + 8 * lg);

        f32x4 sc2[2] = {{0.f,0.f,0.f,0.f},{0.f,0.f,0.f,0.f}};
        f32x4 sc1[2] = {{0.f,0.f,0.f,0.f},{0.f,0.f,0.f,0.f}};
        __builtin_amdgcn_s_setprio(1);
#pragma unroll
        for (int sub = 0; sub < 2; ++sub) {
            sc2[sub] = mfma16(kf[sub][0], q2[0], sc2[sub]);
            sc2[sub] = mfma16(kf[sub][1], q2[1], sc2[sub]);
        }
        if (act1) {
#pragma unroll
            for (int sub = 0; sub < 2; ++sub) {
                sc1[sub] = mfma16(kf[sub][0], q1[0], sc1[sub]);
                sc1[sub] = mfma16(kf[sub][1], q1[1], sc1[sub]);
            }
        }
        __builtin_amdgcn_s_setprio(0);
        s16x8 pa;
#pragma unroll
        for (int sub = 0; sub < 2; ++sub)
#pragma unroll
            for (int r = 0; r < 4; ++r) {
                int j = j0 + sub * 16 + 4 * lg + r;
                float p = (j <= ir2) ? fexp(sc2[sub][r] * 0.125f) : 0.f;
                l2 += p;
                pa[sub * 4 + r] = (short)f2bf(p);
            }
        __builtin_amdgcn_s_setprio(1);
#pragma unroll
        for (int ds = 0; ds < 4; ++ds) o2[ds] = mfma16(pa, vfr[ds], o2[ds]);
        __builtin_amdgcn_s_setprio(0);
        if (act1) {
#pragma unroll
            for (int sub = 0; sub < 2; ++sub)
#pragma unroll
                for (int r = 0; r < 4; ++r) {
                    int j = j0 + sub * 16 + 4 * lg + r;
                    float p = (j <= ir1) ? fexp(sc1[sub][r] * 0.125f) : 0.f;
                    l1 += p;
                    pa[sub * 4 + r] = (short)f2bf(p);
                }
            __builtin_amdgcn_s_setprio(1);
#pragma unroll
            for (int ds = 0; ds < 4; ++ds) o1[ds] = mfma16(pa, vfr[ds], o1[ds]);
            __builtin_amdgcn_s_setprio(0);
        }
    }
    l1 += __shfl_xor(l1, 16); l1 += __shfl_xor(l1, 32);
    l2 += __shfl_xor(l2, 16); l2 += __shfl_xor(l2, 32);
    float li1[4], li2[4];
#pragma unroll
    for (int r = 0; r < 4; ++r) {
        li1[r] = 1.f / __shfl(l1, 4 * lg + r);
        li2[r] = 1.f / __shfl(l2, 4 * lg + r);
    }
#pragma unroll
    for (int ds = 0; ds < 4; ++ds)
#pragma unroll
        for (int r = 0; r < 4; ++r) {
            P[(rowBase + i0_1 + 4 * lg + r) * LDP + (C_QSA + h * 64) + ds * 16 + lr] =
                f2bf(o1[ds][r] * li1[r]);
            P[(rowBase + i0_2 + 4 * lg + r) * LDP + (C_QSA + h * 64) + ds * 16 + lr] =
                f2bf(o2[ds][r] * li2[r]);
        }
}

// ---------------- RA attention v5 (R13 + T5 setprio on MFMA clusters) ---------
// 512 blocks x 512 thr. bid&7 = (s,b) XCD slot (parity s), xt = 63-(bid>>3).
// Wave w: head w, rel channel w. Per iter: j-tiles {jt, jt+2}, relT
// double-buffered -> ONE barrier. No max/rescale anywhere.
// Writes RAW partials (l, o, rm); merge_ra combines parity splits.

__global__ __launch_bounds__(512) void attn_ra(u16* __restrict__ P, const u16* __restrict__ SVt,
                                               float* __restrict__ opart,
                                               float* __restrict__ mlr) {
    const int bid = blockIdx.x;
    const int slot = bid & 7;
    const int b = slot & 3, s = slot >> 2;
    const int xt = 63 - (bid >> 3);
    const int w = threadIdx.x >> 6, lane = threadIdx.x & 63;
    const int lr = lane & 15, lg = lane >> 4;
    const int h = w;
    const size_t rowBase = (size_t)b * 1024;
    const int i0 = xt * 16;
    const int ir = i0 + lr;

    __shared__ float relT[2][2][32][16][8];   // [dbuf][tileAB][j-local][i][swz slot]

    const u16* Kbase  = P + rowBase * LDP + (C_KA + h * 64);
    const u16* KRbase = P + rowBase * LDP + (C_KR + h * 64);
    const u16* Vb = SVt + ((size_t)(b * 8 + h)) * 65536;

    s16x8 qf[2], qrf[2];
    {
        const u16* q = P + (rowBase + ir) * LDP + (C_QA + h * 64) + lg * 8;
        qf[0] = *(const s16x8*)q; qf[1] = *(const s16x8*)(q + 32);
        const u16* qr = P + (rowBase + ir) * LDP + (C_QR + h * 64) + lg * 8;
        qrf[0] = *(const s16x8*)qr; qrf[1] = *(const s16x8*)(qr + 32);
    }
    f32x4 o[4] = {};
    float rmr[8] = {};                      // rotated slots: slot k = channel (k-lr)&7
    float l = 0.f;
    const int njt = (xt >> 1) + 1;
    const int cnt = (njt - s + 1) >> 1;     // tiles of parity s
    const int npair = (cnt + 1) >> 1;
    const int slotw = (w + lr) & 7;

    for (int u = 0; u < npair; ++u) {
        const int j0a = (s + 4 * u) * 32;
        const bool actB = (2 * u + 1) < cnt;        // block-uniform
        const int j0b = actB ? j0a + 64 : j0a;      // clamp for safe loads
        // ---- K / K_rel / V loads ----
        s16x8 kfA[2][2], krA[2][2], kfB[2][2], krB[2][2], vfA[4], vfB[4];
#pragma unroll
        for (int sub = 0; sub < 2; ++sub) {
            const u16* kp = Kbase + (size_t)(j0a + sub * 16 + lr) * LDP + lg * 8;
            kfA[sub][0] = *(const s16x8*)kp;  kfA[sub][1] = *(const s16x8*)(kp + 32);
            const u16* krp = KRbase + (size_t)(j0a + sub * 16 + lr) * LDP + lg * 8;
            krA[sub][0] = *(const s16x8*)krp; krA[sub][1] = *(const s16x8*)(krp + 32);
            kp = Kbase + (size_t)(j0b + sub * 16 + lr) * LDP + lg * 8;
            kfB[sub][0] = *(const s16x8*)kp;  kfB[sub][1] = *(const s16x8*)(kp + 32);
            krp = KRbase + (size_t)(j0b + sub * 16 + lr) * LDP + lg * 8;
            krB[sub][0] = *(const s16x8*)krp; krB[sub][1] = *(const s16x8*)(krp + 32);
        }
#pragma unroll
        for (int ds = 0; ds < 4; ++ds) {
            vfA[ds] = *(const s16x8*)(Vb + (size_t)(ds * 16 + lr) * 1024 + j0a + 8 * lg);
            vfB[ds] = *(const s16x8*)(Vb + (size_t)(ds * 16 + lr) * 1024 + j0b + 8 * lg);
        }
        // ---- MFMAs (priority-boosted cluster) ----
        f32x4 scA[2] = {{0.f,0.f,0.f,0.f},{0.f,0.f,0.f,0.f}};
        f32x4 scB[2] = {{0.f,0.f,0.f,0.f},{0.f,0.f,0.f,0.f}};
        f32x4 rtA[2] = {{0.f,0.f,0.f,0.f},{0.f,0.f,0.f,0.f}};
        f32x4 rtB[2] = {{0.f,0.f,0.f,0.f},{0.f,0.f,0.f,0.f}};
        __builtin_amdgcn_s_setprio(1);
#pragma unroll
        for (int sub = 0; sub < 2; ++sub) {
            scA[sub] = mfma16(kfA[sub][0], qf[0], scA[sub]);
            scA[sub] = mfma16(kfA[sub][1], qf[1], scA[sub]);
            rtA[sub] = mfma16(krA[sub][0], qrf[0], rtA[sub]);
            rtA[sub] = mfma16(krA[sub][1], qrf[1], rtA[sub]);
            scB[sub] = mfma16(kfB[sub][0], qf[0], scB[sub]);
            scB[sub] = mfma16(kfB[sub][1], qf[1], scB[sub]);
            rtB[sub] = mfma16(krB[sub][0], qrf[0], rtB[sub]);
            rtB[sub] = mfma16(krB[sub][1], qrf[1], rtB[sub]);
        }
        __builtin_amdgcn_s_setprio(0);
        // ---- p = exp(s) (no max), accumulate l, pack ----
        float pA[2][4], pB[2][4];
#pragma unroll
        for (int sub = 0; sub < 2; ++sub)
#pragma unroll
            for (int r = 0; r < 4; ++r) {
                int jA = j0a + sub * 16 + 4 * lg + r;
                int jB = j0b + sub * 16 + 4 * lg + r;
                pA[sub][r] = (jA <= ir) ? fexp(scA[sub][r] * 0.125f) : 0.f;
                pB[sub][r] = (actB && jB <= ir) ? fexp(scB[sub][r] * 0.125f) : 0.f;
                l += pA[sub][r] + pB[sub][r];
            }
        // ---- publish tanh(rel) (double-buffered), ONE barrier ----
#pragma unroll
        for (int sub = 0; sub < 2; ++sub)
#pragma unroll
            for (int r = 0; r < 4; ++r) {
                int jp = sub * 16 + 4 * lg + r;
                relT[u & 1][0][jp][lr][slotw] = ftanh(rtA[sub][r] * 0.125f);
                relT[u & 1][1][jp][lr][slotw] = ftanh(rtB[sub][r] * 0.125f);
            }
        __syncthreads();
        // ---- accumulate p * rel, all 8 slots, both tiles ----
#pragma unroll
        for (int sub = 0; sub < 2; ++sub)
#pragma unroll
            for (int r = 0; r < 4; ++r) {
                int jp = sub * 16 + 4 * lg + r;
                f32x4 a  = *(const f32x4*)&relT[u & 1][0][jp][lr][0];
                f32x4 bb = *(const f32x4*)&relT[u & 1][0][jp][lr][4];
                float pv = pA[sub][r];
#pragma unroll
                for (int k = 0; k < 4; ++k) {
                    rmr[k]     += pv * a[k];
                    rmr[4 + k] += pv * bb[k];
                }
                a  = *(const f32x4*)&relT[u & 1][1][jp][lr][0];
                bb = *(const f32x4*)&relT[u & 1][1][jp][lr][4];
                pv = pB[sub][r];
#pragma unroll
                for (int k = 0; k < 4; ++k) {
                    rmr[k]     += pv * a[k];
                    rmr[4 + k] += pv * bb[k];
                }
            }
        // ---- PV (no rescale, priority-boosted) ----
        s16x8 paA, paB;
#pragma unroll
        for (int r = 0; r < 4; ++r) {
            paA[r]     = (short)f2bf(pA[0][r]);
            paA[4 + r] = (short)f2bf(pA[1][r]);
            paB[r]     = (short)f2bf(pB[0][r]);
            paB[4 + r] = (short)f2bf(pB[1][r]);
        }
        __builtin_amdgcn_s_setprio(1);
#pragma unroll
        for (int ds = 0; ds < 4; ++ds) {
            o[ds] = mfma16(paA, vfA[ds], o[ds]);
            o[ds] = mfma16(paB, vfB[ds], o[ds]);
        }
        __builtin_amdgcn_s_setprio(0);
    }

    // ---- epilogue: reduce l and rotated slots, un-rotate, write partials ----
    l += __shfl_xor(l, 16); l += __shfl_xor(l, 32);
#pragma unroll
    for (int k = 0; k < 8; ++k) {
        float v = rmr[k];
        v += __shfl_xor(v, 16);
        v += __shfl_xor(v, 32);
        rmr[k] = v;
    }
    float g[8], t0[8];
    const int t = lr & 7;
#pragma unroll
    for (int k = 0; k < 8; ++k) g[k] = rmr[k];
#pragma unroll
    for (int k = 0; k < 8; ++k) t0[k] = (t & 1) ? g[(k + 1) & 7] : g[k];
#pragma unroll
    for (int k = 0; k < 8; ++k) g[k]  = (t & 2) ? t0[(k + 2) & 7] : t0[k];
#pragma unroll
    for (int k = 0; k < 8; ++k) t0[k] = (t & 4) ? g[(k + 4) & 7] : g[k];

    const int headRow = (b * 8 + h) * 1024;
#pragma unroll
    for (int ds = 0; ds < 4; ++ds)
#pragma unroll
        for (int r = 0; r < 4; ++r) {
            int row = headRow + i0 + 4 * lg + r;
            opart[((size_t)row * 2 + s) * 64 + ds * 16 + lr] = o[ds][r];
        }
    if (lg == 0) {
        float* pm = &mlr[((size_t)(headRow + i0 + lr) * 2 + s) * 10];
        pm[0] = l;
#pragma unroll
        for (int c = 0; c < 8; ++c) pm[1 + c] = t0[c];
    }
}

// ---------------- RA merge: (o0+o1)/(l0+l1), wr projection, write Pcat --------

__global__ __launch_bounds__(256) void merge_ra(const float* __restrict__ opart,
                                                const float* __restrict__ mlr,
                                                const float* __restrict__ wr,
                                                u16* __restrict__ P) {
    const int gid = blockIdx.x * 4 + (threadIdx.x >> 6);   // [0, 32768)
    const int d = threadIdx.x & 63;
    const int i = gid & 1023;
    const int h = (gid >> 10) & 7;
    const int b = gid >> 13;
    const float* ml0 = &mlr[(size_t)gid * 20];
    const float* ml1 = ml0 + 10;
    float ilt = 1.f / (ml0[0] + ml1[0]);
    float acc = (opart[(size_t)gid * 128 + d] +
                 opart[(size_t)gid * 128 + 64 + d]) * ilt;
#pragma unroll
    for (int c = 0; c < 8; ++c) {
        float rm = (ml0[1 + c] + ml1[1 + c]) * ilt;
        acc += rm * wr[h * 512 + d * 8 + c];
    }
    P[((size_t)(b * 1024 + i)) * LDP + C_QA + h * 64 + d] = f2bf(acc);
}

// ---------------- launcher ----------------

extern "C" void kernel_launch(void* const* d_in, const int* in_sizes, int n_in,
                              void* d_out, int out_size, void* d_ws, size_t ws_size,
                              hipStream_t stream)
{
    const float* x     = (const float*)d_in[0];
    const float* sym   = (const float*)d_in[1];
    const float* fcos  = (const float*)d_in[2];
    const float* fsin  = (const float*)d_in[3];
    const float* w_qsa = (const float*)d_in[4];
    const float* w_ksa = (const float*)d_in[5];
    const float* w_vsa = (const float*)d_in[6];
    const float* w_osa = (const float*)d_in[7];
    const float* w_qa  = (const float*)d_in[8];
    const float* w_ka  = (const float*)d_in[9];
    const float* w_qr  = (const float*)d_in[10];
    const float* w_kr  = (const float*)d_in[11];
    const float* wr    = (const float*)d_in[12];
    const float* w_sv  = (const float*)d_in[13];
    const float* w_ora = (const float*)d_in[14];

    char* ws = (char*)d_ws;
    u16* xb    = (u16*)(ws);                                  // 8 MB   (dead after proj GEMM)
    u16* symb  = (u16*)(ws + (8u  << 20));                    // 8 MB   (dead after proj GEMM)
    u16* WcatT = (u16*)(ws + (16u << 20));                    // 8 MB   (dead after proj GEMM)
    u16* woSaT = (u16*)(ws + (24u << 20));                    // 512 KB
    u16* woRaT = (u16*)(ws + (24u << 20) + (512u << 10));     // 512 KB
    u16* Pcat  = (u16*)(ws + (25u << 20));                    // 32 MB
    u16* vT    = (u16*)(ws + (57u << 20));                    // 4 MB
    u16* svT   = (u16*)(ws + (61u << 20));                    // 4 MB
    // RA partials reuse the dead 0..24 MB region after the projection GEMM:
    float* opart = (float*)(ws);                              // 16.78 MB
    float* mlrp  = (float*)(ws + (17u << 20));                // 2.62 MB

    cvt2_f32_bf16<<<4096, 256, 0, stream>>>(x, sym, xb, symb);

    WP wp{{w_qsa, w_ksa, w_vsa, w_qa, w_ka, w_qr, w_kr, w_sv, w_osa, w_ora}};
    transpose_w<<<dim3(32, 16, 10), 256, 0, stream>>>(wp, WcatT, woSaT, woRaT);

    gemm_bf16<true, true><<<dim3(32, 32), 256, 0, stream>>>(
        xb, symb, 1024, C_SV, WcatT, 1024, Pcat, LDP, 0, 1024);

    rope_kernel<<<16384, 256, 0, stream>>>(Pcat, fcos, fsin);

    transpose_v2<<<dim3(32, 16, 4), 256, 0, stream>>>(Pcat, vT,  C_VSA);
    transpose_v2<<<dim3(32, 16, 4), 256, 0, stream>>>(Pcat, svT, C_SV);

    attn_sa<<<1024, 64, 0, stream>>>(Pcat, vT);
    attn_ra<<<512, 512, 0, stream>>>(Pcat, svT, opart, mlrp);
    merge_ra<<<8192, 256, 0, stream>>>(opart, mlrp, wr, Pcat);

    // merged output projection: cols [0,512) = wo_sa @ sa_out, [512,1024) = wo_ra @ ra_out
    gemm_bf16<false, false><<<dim3(32, 8), 256, 0, stream>>>(
        Pcat + C_QSA, Pcat + C_QA, LDP, 512, woSaT, 512, d_out, 1024, 0, 512);
}